// Round 2
// baseline (6397.155 us; speedup 1.0000x reference)
//
#include <hip/hip_runtime.h>
#include <hip/hip_bf16.h>

typedef __bf16 bf16x8 __attribute__((ext_vector_type(8)));
typedef __bf16 bf16x4 __attribute__((ext_vector_type(4)));
typedef float  f32x4  __attribute__((ext_vector_type(4)));

#define MFMA16(a, b, c) __builtin_amdgcn_mfma_f32_16x16x32_bf16((a), (b), (c), 0, 0, 0)
#define GLD16(gptr, lptr) __builtin_amdgcn_global_load_lds( \
    (__attribute__((address_space(1))) void*)(const void*)(gptr), \
    (__attribute__((address_space(3))) void*)(lptr), 16, 0, 0)

#define BS   32
#define TS   256
#define TT   64
#define EDIM 256
#define HDIM 512
#define H4   2048
#define VT   32000
#define XDIM 768   // E + H
#define OCAT 1024  // 2H

// ---- ws layout (bytes); every size is a multiple of 256 ----
constexpr size_t WS_CNT     = 0;                         // unsigned[64]
constexpr size_t WS_ENCWXT  = 256;                       // bf16 [2048][256]
constexpr size_t WS_ENCWHT  = WS_ENCWXT + 1048576;       // bf16 [2048][512]
constexpr size_t WS_DECWXT  = WS_ENCWHT + 2097152;       // bf16 [2048][768]
constexpr size_t WS_DECWHT  = WS_DECWXT + 3145728;       // bf16 [2048][512]
constexpr size_t WS_ATTNWHT = WS_DECWHT + 2097152;       // bf16 [512][512]
constexpr size_t WS_WST     = WS_ATTNWHT + 524288;       // f32  [512][512]  (attn_Ws^T)
constexpr size_t WS_OUTWT   = WS_WST + 1048576;          // bf16 [32000][1024]
constexpr size_t WS_EMBA    = WS_OUTWT + 65536000;       // bf16 [8192][256]
constexpr size_t WS_HCAT    = WS_EMBA + 4194304;         // bf16 [2048][1024]
constexpr size_t WS_HENC    = WS_HCAT + 4194304;         // bf16 2x[32][512]
constexpr size_t WS_CFIN    = WS_HENC + 65536;           // f32  [32][512]
constexpr size_t WS_HDEC    = WS_CFIN + 65536;           // bf16 2x[32][512]
constexpr size_t WS_XDEC    = WS_HDEC + 65536;           // bf16 [32][768]
constexpr size_t WS_SBUF    = WS_XDEC + 49152;           // f32  [32][512]
constexpr size_t WS_EBUF    = WS_SBUF + 65536;           // f32  [32][256]
// total ~80.4 MB

// ---- d_out used as scratch before the final GEMM overwrites it ----
constexpr size_t DO_SRCZX = 0;          // bf16 [8192][2048]  (32 MB)
constexpr size_t DO_WHENC = 33554432;   // f32  [8192][512]   (16.78 MB)
constexpr size_t DO_ENCHS = 50331648;   // bf16 [8192][512]   (8.39 MB)

__device__ __forceinline__ float sigm(float x) {
  return __fdividef(1.f, 1.f + __expf(-x));
}
__device__ __forceinline__ float tanh_f(float x) {
  float e = __expf(2.f * x);
  return 1.f - __fdividef(2.f, e + 1.f);
}

// agent-scope grid barrier; counter monotonic (re-zeroed each launch by zero_init).
// arrive = RELEASE (flushes this XCD's dirty L2 lines), spin = RELAXED (polls MALL,
// no per-poll cache maintenance), depart = one ACQUIRE load (invalidates stale L1/L2).
__device__ __forceinline__ void grid_bar(unsigned* cnt, unsigned target) {
  __syncthreads();
  if (threadIdx.x == 0) {
    __hip_atomic_fetch_add(cnt, 1u, __ATOMIC_RELEASE, __HIP_MEMORY_SCOPE_AGENT);
    while (__hip_atomic_load(cnt, __ATOMIC_RELAXED, __HIP_MEMORY_SCOPE_AGENT) < target)
      __builtin_amdgcn_s_sleep(2);
    (void)__hip_atomic_load(cnt, __ATOMIC_ACQUIRE, __HIP_MEMORY_SCOPE_AGENT);
  }
  __syncthreads();
}

// ---------------------------------------------------------------------------
__global__ __launch_bounds__(256) void zero_init(unsigned* __restrict__ cnt,
                                                 unsigned* __restrict__ henc) {
  const int i = blockIdx.x * 256 + threadIdx.x;   // grid 64x256 = 16384
  if (i < 64) cnt[i] = 0;
  henc[i] = 0;  // 2*32*512 bf16 = 16384 u32 exactly
}

// in f32 [R][C] -> out [C][R] (cast to OutT)
template <typename OutT>
__global__ __launch_bounds__(256) void transpose_cvt(const float* __restrict__ in,
                                                     OutT* __restrict__ out,
                                                     int R, int C) {
  __shared__ float tile[32][33];
  const int c0 = blockIdx.x * 32, r0 = blockIdx.y * 32;
  const int cx = threadIdx.x & 31, ry = threadIdx.x >> 5;
  #pragma unroll
  for (int rr = ry; rr < 32; rr += 8)
    tile[rr][cx] = in[(size_t)(r0 + rr) * C + c0 + cx];
  __syncthreads();
  #pragma unroll
  for (int cc = ry; cc < 32; cc += 8)
    out[(size_t)(c0 + cc) * R + r0 + cx] = (OutT)tile[cx][cc];
}

__global__ __launch_bounds__(256) void embed_src(const int* __restrict__ src,
                                                 const float* __restrict__ emb,
                                                 __bf16* __restrict__ out) {
  const int r = blockIdx.x;
  const int idx = src[r];
  out[(size_t)r * EDIM + threadIdx.x] = (__bf16)emb[(size_t)idx * EDIM + threadIdx.x];
}

// ---------------------------------------------------------------------------
// 128x128 tile MFMA GEMM, BK=32, global_load_lds staging (m97 structure).
// A [M][K] bf16 row-major; BT [N][K] bf16 (B transposed); M,N %128==0, K%32==0.
// EPI: 0 = f32 store, 1 = bf16 store + bias, 2 = f32 store + bias + (t,b)->(b,t) row permute
template <int EPI>
__global__ __launch_bounds__(256, 2) void gemm128(const __bf16* __restrict__ A,
                                                  const __bf16* __restrict__ BT,
                                                  const float* __restrict__ bias,
                                                  void* __restrict__ Cout,
                                                  int M, int N, int K) {
  const int m0 = blockIdx.x * 128;
  const int n0 = blockIdx.y * 128;
  const int tid = threadIdx.x, lane = tid & 63, wv = tid >> 6;
  const int wm = wv >> 1, wn = wv & 1;
  __shared__ __bf16 As[128 * 32];
  __shared__ __bf16 Bs[128 * 32];
  f32x4 acc[16];
  #pragma unroll
  for (int i = 0; i < 16; ++i) acc[i] = (f32x4){0.f, 0.f, 0.f, 0.f};

  const int srow = tid >> 2, skb = (tid & 3) * 8;
  const __bf16* agp  = A  + (size_t)(m0 + srow) * K + skb;
  const __bf16* agp2 = A  + (size_t)(m0 + 64 + srow) * K + skb;
  const __bf16* bgp  = BT + (size_t)(n0 + srow) * K + skb;
  const __bf16* bgp2 = BT + (size_t)(n0 + 64 + srow) * K + skb;
  __bf16* asb  = As + wv * 512;          // wave-uniform LDS bases; HW adds lane*16B
  __bf16* asb2 = As + 2048 + wv * 512;
  __bf16* bsb  = Bs + wv * 512;
  __bf16* bsb2 = Bs + 2048 + wv * 512;

  const int l15 = lane & 15, kq = (lane >> 4) * 8;

  for (int k0 = 0; k0 < K; k0 += 32) {
    __syncthreads();
    GLD16(agp + k0, asb);
    GLD16(agp2 + k0, asb2);
    GLD16(bgp + k0, bsb);
    GLD16(bgp2 + k0, bsb2);
    __syncthreads();
    bf16x8 af[4], bfr[4];
    #pragma unroll
    for (int f = 0; f < 4; ++f)
      af[f] = *reinterpret_cast<const bf16x8*>(As + (wm * 64 + f * 16 + l15) * 32 + kq);
    #pragma unroll
    for (int f = 0; f < 4; ++f)
      bfr[f] = *reinterpret_cast<const bf16x8*>(Bs + (wn * 64 + f * 16 + l15) * 32 + kq);
    #pragma unroll
    for (int fi = 0; fi < 4; ++fi)
      #pragma unroll
      for (int fj = 0; fj < 4; ++fj)
        acc[fi * 4 + fj] = MFMA16(af[fi], bfr[fj], acc[fi * 4 + fj]);
  }

  const int rq = (lane >> 4) * 4;
  #pragma unroll
  for (int fi = 0; fi < 4; ++fi) {
    #pragma unroll
    for (int fj = 0; fj < 4; ++fj) {
      const int col = n0 + wn * 64 + fj * 16 + l15;
      float bv = 0.f;
      if (EPI >= 1) bv = bias[col];
      #pragma unroll
      for (int r = 0; r < 4; ++r) {
        const int row = m0 + wm * 64 + fi * 16 + rq + r;
        float v = acc[fi * 4 + fj][r] + bv;
        if (EPI == 1) {
          ((__bf16*)Cout)[(size_t)row * N + col] = (__bf16)v;
        } else if (EPI == 2) {
          const int orow = (row & 31) * 64 + (row >> 5);  // row = t*32+b -> b*64+t
          ((float*)Cout)[(size_t)orow * N + col] = v;
        } else {
          ((float*)Cout)[(size_t)row * N + col] = v;
        }
      }
    }
  }
}

// ---------------------------------------------------------------------------
// Persistent encoder: 64 WGs, WG g owns z cols {G*512 + g*8 + 0..7} for G=0..3.
// Per step: z[32x32] = h @ Wh-slice (MFMA, B-slice held in 64 VGPRs) + zx + bh.
__global__ __launch_bounds__(256, 1) void encoder_kernel(
    const __bf16* __restrict__ zx,   // [BS*TS][H4] incl. enc_bx
    const __bf16* __restrict__ WhT,  // [H4][HDIM]
    const float* __restrict__ bh,    // [H4]
    __bf16* __restrict__ h_pp,       // 2 x [BS][HDIM]
    __bf16* __restrict__ enc_hs,     // [BS*TS][HDIM]
    float* __restrict__ c_fin,       // [BS][HDIM]
    unsigned* __restrict__ cnt) {
  const int blk = blockIdx.x, tid = threadIdx.x;
  const int lane = tid & 63, wv = tid >> 6, rh = wv >> 1, ch = wv & 1;
  const int l15 = lane & 15, kb = (lane >> 4) * 8;
  __shared__ float z_lds[32][33];

  const int cv = ch * 16 + l15;
  const int ca = (cv >> 3) * HDIM + blk * 8 + (cv & 7);
  bf16x8 Bf[16];
  #pragma unroll
  for (int ks = 0; ks < 16; ++ks)
    Bf[ks] = *reinterpret_cast<const bf16x8*>(WhT + (size_t)ca * HDIM + ks * 32 + kb);

  const int b8 = tid >> 3, hd = tid & 7;
  const int hidx = blk * 8 + hd;
  float bh4[4];
  #pragma unroll
  for (int G = 0; G < 4; ++G) bh4[G] = bh[G * HDIM + hidx];
  float c = 0.f;
  const int arow = rh * 16 + l15;

  for (int t = 0; t < TS; ++t) {
    const __bf16* hb = h_pp + (t & 1) * (BS * HDIM) + arow * HDIM;
    float zx4[4];
    #pragma unroll
    for (int G = 0; G < 4; ++G)
      zx4[G] = (float)zx[(size_t)(b8 * TS + t) * H4 + G * HDIM + hidx];

    f32x4 acc = {0.f, 0.f, 0.f, 0.f};
    #pragma unroll
    for (int ks = 0; ks < 16; ++ks) {
      bf16x8 a = *reinterpret_cast<const bf16x8*>(hb + ks * 32 + kb);
      acc = MFMA16(a, Bf[ks], acc);
    }
    #pragma unroll
    for (int r = 0; r < 4; ++r)
      z_lds[rh * 16 + (lane >> 4) * 4 + r][cv] = acc[r];
    __syncthreads();

    float zi = z_lds[b8][hd]      + zx4[0] + bh4[0];
    float zf = z_lds[b8][8 + hd]  + zx4[1] + bh4[1];
    float zg = z_lds[b8][16 + hd] + zx4[2] + bh4[2];
    float zo = z_lds[b8][24 + hd] + zx4[3] + bh4[3];
    c = sigm(zf) * c + sigm(zi) * tanh_f(zg);
    float h = sigm(zo) * tanh_f(c);
    __bf16 h16 = (__bf16)h;
    h_pp[((t + 1) & 1) * (BS * HDIM) + b8 * HDIM + hidx] = h16;
    enc_hs[(size_t)(b8 * TS + t) * HDIM + hidx] = h16;
    if (t == TS - 1) c_fin[b8 * HDIM + hidx] = c;
    grid_bar(cnt, 64u * (t + 1));
  }
}

// ---------------------------------------------------------------------------
// Persistent decoder: 64 WGs, 4 phases/step, 4 grid barriers/step.
__global__ __launch_bounds__(256, 1) void decoder_kernel(
    const int* __restrict__ tgt,         // [BS][TT]
    const float* __restrict__ dec_embed, // [VT][EDIM]
    const float* __restrict__ WsT,       // [HDIM][HDIM] = attn_Ws^T
    const float* __restrict__ attn_v,    // [HDIM]
    const float* __restrict__ whenc,     // [BS*TS][HDIM] f32
    const __bf16* __restrict__ enc_hs,   // [BS*TS][HDIM]
    const __bf16* __restrict__ WxT,      // [H4][XDIM]
    const __bf16* __restrict__ WhT,      // [H4][HDIM]
    const float* __restrict__ bx,        // [H4]
    const float* __restrict__ bh,        // [H4]
    const float* __restrict__ c_fin,     // [BS][HDIM]
    __bf16* __restrict__ h_pp,           // 2 x [BS][HDIM]
    __bf16* __restrict__ x_dec,          // [BS][XDIM]
    float* __restrict__ s_buf,           // [BS][HDIM]
    float* __restrict__ e_buf,           // [BS][TS]
    __bf16* __restrict__ Hcat,           // [TT*BS][OCAT]
    unsigned* __restrict__ cnt) {
  const int blk = blockIdx.x, tid = threadIdx.x;
  const int lane = tid & 63, wv = tid >> 6, rh = wv >> 1, ch = wv & 1;
  const int l15 = lane & 15, kb = (lane >> 4) * 8;
  __shared__ float z_lds[32][33];
  __shared__ float ep_lds[128][2];
  __shared__ float red[8];
  __shared__ float attn_lds[256];

  // dec weight slice in registers: 24 Wx-frags + 16 Wh-frags = 160 VGPR/lane
  const int cv = ch * 16 + l15;
  const int ca = (cv >> 3) * HDIM + blk * 8 + (cv & 7);
  bf16x8 Bf[40];
  #pragma unroll
  for (int ks = 0; ks < 24; ++ks)
    Bf[ks] = *reinterpret_cast<const bf16x8*>(WxT + (size_t)ca * XDIM + ks * 32 + kb);
  #pragma unroll
  for (int ks = 0; ks < 16; ++ks)
    Bf[24 + ks] = *reinterpret_cast<const bf16x8*>(WhT + (size_t)ca * HDIM + ks * 32 + kb);

  const int b8 = tid >> 3, hd = tid & 7;
  const int hidx = blk * 8 + hd;
  float bb4[4];
  #pragma unroll
  for (int G = 0; G < 4; ++G) bb4[G] = bx[G * HDIM + hidx] + bh[G * HDIM + hidx];
  float c = c_fin[b8 * HDIM + hidx];
  h_pp[b8 * HDIM + hidx] = enc_hs[(size_t)(b8 * TS + TS - 1) * HDIM + hidx];

  unsigned bt = 64;
  grid_bar(cnt, bt);
  const int arow = rh * 16 + l15;

  for (int t = 0; t < TT; ++t) {
    const int cur = t & 1, nxt = cur ^ 1;
    const __bf16* hcur = h_pp + cur * (BS * HDIM);

    // ---- P1: s = h @ attn_Ws ; WG owns 8 cols for all 32 rows ----
    {
      const int col = blk * 8 + (tid & 7);
      const __bf16* hrow = hcur + (tid >> 3) * HDIM;
      const float* wcol = WsT + (size_t)col * HDIM;
      float a0 = 0.f, a1 = 0.f;
      #pragma unroll 2
      for (int k = 0; k < HDIM; k += 8) {
        bf16x4 h0 = *reinterpret_cast<const bf16x4*>(hrow + k);
        bf16x4 h1 = *reinterpret_cast<const bf16x4*>(hrow + k + 4);
        float4 w0 = *reinterpret_cast<const float4*>(wcol + k);
        float4 w1 = *reinterpret_cast<const float4*>(wcol + k + 4);
        a0 += (float)h0[0] * w0.x + (float)h0[1] * w0.y + (float)h0[2] * w0.z + (float)h0[3] * w0.w;
        a1 += (float)h1[0] * w1.x + (float)h1[1] * w1.y + (float)h1[2] * w1.z + (float)h1[3] * w1.w;
      }
      s_buf[(tid >> 3) * HDIM + col] = a0 + a1;
    }
    grid_bar(cnt, bt += 64);

    // ---- P2: energies; WG = (b = blk>>1, t-half); 2 threads per t' (h-halves) ----
    {
      const int b = blk >> 1, tb = (blk & 1) * 128;
      const int tp = tb + (tid >> 1), hh = (tid & 1) * 256;
      const float* wrow = whenc + (size_t)(b * TS + tp) * HDIM + hh;
      const float* srow = s_buf + b * HDIM + hh;
      const float* vrow = attn_v + hh;
      float acc = 0.f;
      #pragma unroll 2
      for (int h = 0; h < 256; h += 4) {
        float4 wvv = *reinterpret_cast<const float4*>(wrow + h);
        float4 sv = *reinterpret_cast<const float4*>(srow + h);
        float4 vv = *reinterpret_cast<const float4*>(vrow + h);
        acc += vv.x * tanh_f(wvv.x + sv.x) + vv.y * tanh_f(wvv.y + sv.y)
             + vv.z * tanh_f(wvv.z + sv.z) + vv.w * tanh_f(wvv.w + sv.w);
      }
      ep_lds[tid >> 1][tid & 1] = acc;
      __syncthreads();
      if (tid < 128) e_buf[b * TS + tb + tid] = ep_lds[tid][0] + ep_lds[tid][1];
    }
    grid_bar(cnt, bt += 64);

    // ---- P3: softmax (shuffle-reduce) + ctx + target embedding ----
    {
      const int b = blk >> 1, hbase = (blk & 1) * 256;
      const float ev = e_buf[b * TS + tid];
      float m = ev;
      #pragma unroll
      for (int o = 32; o > 0; o >>= 1) m = fmaxf(m, __shfl_xor(m, o));
      if (lane == 0) red[wv] = m;
      __syncthreads();
      m = fmaxf(fmaxf(red[0], red[1]), fmaxf(red[2], red[3]));
      const float p = __expf(ev - m);
      float sum = p;
      #pragma unroll
      for (int o = 32; o > 0; o >>= 1) sum += __shfl_xor(sum, o);
      if (lane == 0) red[4 + wv] = sum;
      __syncthreads();
      sum = (red[4] + red[5]) + (red[6] + red[7]);
      attn_lds[tid] = p * __fdividef(1.f, sum);
      __syncthreads();
      {
        const int hpp = hbase + tid;
        float a0 = 0.f, a1 = 0.f, a2 = 0.f, a3 = 0.f;
        for (int tp = 0; tp < TS; tp += 4) {
          a0 = fmaf(attn_lds[tp],     (float)enc_hs[(size_t)(b * TS + tp) * HDIM + hpp], a0);
          a1 = fmaf(attn_lds[tp + 1], (float)enc_hs[(size_t)(b * TS + tp + 1) * HDIM + hpp], a1);
          a2 = fmaf(attn_lds[tp + 2], (float)enc_hs[(size_t)(b * TS + tp + 2) * HDIM + hpp], a2);
          a3 = fmaf(attn_lds[tp + 3], (float)enc_hs[(size_t)(b * TS + tp + 3) * HDIM + hpp], a3);
        }
        const float ctx = (a0 + a1) + (a2 + a3);
        x_dec[b * XDIM + EDIM + hpp] = (__bf16)ctx;
        Hcat[(size_t)(t * BS + b) * OCAT + HDIM + hpp] = (__bf16)ctx;
      }
      if ((blk & 1) == 0) {
        const int tg = tgt[b * TT + t];
        x_dec[b * XDIM + tid] = (__bf16)dec_embed[(size_t)tg * EDIM + tid];
      }
    }
    grid_bar(cnt, bt += 64);

    // ---- P4: z = x@Wx + h@Wh (+biases) via MFMA, then gates ----
    {
      const __bf16* xr = x_dec + arow * XDIM;
      const __bf16* hr = hcur + arow * HDIM;
      f32x4 acc = {0.f, 0.f, 0.f, 0.f};
      #pragma unroll
      for (int ks = 0; ks < 24; ++ks) {
        bf16x8 a = *reinterpret_cast<const bf16x8*>(xr + ks * 32 + kb);
        acc = MFMA16(a, Bf[ks], acc);
      }
      #pragma unroll
      for (int ks = 0; ks < 16; ++ks) {
        bf16x8 a = *reinterpret_cast<const bf16x8*>(hr + ks * 32 + kb);
        acc = MFMA16(a, Bf[24 + ks], acc);
      }
      #pragma unroll
      for (int r = 0; r < 4; ++r)
        z_lds[rh * 16 + (lane >> 4) * 4 + r][cv] = acc[r];
    }
    __syncthreads();
    {
      float zi = z_lds[b8][hd]      + bb4[0];
      float zf = z_lds[b8][8 + hd]  + bb4[1];
      float zg = z_lds[b8][16 + hd] + bb4[2];
      float zo = z_lds[b8][24 + hd] + bb4[3];
      c = sigm(zf) * c + sigm(zi) * tanh_f(zg);
      float h = sigm(zo) * tanh_f(c);
      __bf16 h16 = (__bf16)h;
      h_pp[nxt * (BS * HDIM) + b8 * HDIM + hidx] = h16;
      Hcat[(size_t)(t * BS + b8) * OCAT + hidx] = h16;
    }
    grid_bar(cnt, bt += 64);
  }
}

// ---------------------------------------------------------------------------
// in-place log_softmax over rows of 32000 (logits are small; no max shift needed)
__global__ __launch_bounds__(256, 4) void lsm_kernel(float* __restrict__ out) {
  const int row = blockIdx.x;
  float* p = out + (size_t)row * VT;
  __shared__ float wred[4];
  float lsum = 0.f;
  for (int cc = threadIdx.x * 4; cc < VT; cc += 1024) {
    float4 v = *reinterpret_cast<const float4*>(p + cc);
    lsum += __expf(v.x) + __expf(v.y) + __expf(v.z) + __expf(v.w);
  }
  #pragma unroll
  for (int o = 32; o > 0; o >>= 1) lsum += __shfl_down(lsum, o);
  if ((threadIdx.x & 63) == 0) wred[threadIdx.x >> 6] = lsum;
  __syncthreads();
  const float l = logf(wred[0] + wred[1] + wred[2] + wred[3]);
  for (int cc = threadIdx.x * 4; cc < VT; cc += 1024) {
    float4 v = *reinterpret_cast<const float4*>(p + cc);
    v.x -= l; v.y -= l; v.z -= l; v.w -= l;
    *reinterpret_cast<float4*>(p + cc) = v;
  }
}

// ---------------------------------------------------------------------------
extern "C" void kernel_launch(void* const* d_in, const int* in_sizes, int n_in,
                              void* d_out, int out_size, void* d_ws, size_t ws_size,
                              hipStream_t stream) {
  (void)in_sizes; (void)n_in; (void)out_size; (void)ws_size;
  const int*   src       = (const int*)d_in[0];
  const int*   tgt       = (const int*)d_in[1];
  const float* enc_embed = (const float*)d_in[2];
  const float* enc_Wx    = (const float*)d_in[3];
  const float* enc_bx    = (const float*)d_in[4];
  const float* enc_Wh    = (const float*)d_in[5];
  const float* enc_bh    = (const float*)d_in[6];
  const float* dec_embed = (const float*)d_in[7];
  const float* attn_Wh   = (const float*)d_in[8];
  const float* attn_Ws   = (const float*)d_in[9];
  const float* attn_v    = (const float*)d_in[10];
  const float* dec_Wx    = (const float*)d_in[11];
  const float* dec_bx    = (const float*)d_in[12];
  const float* dec_Wh    = (const float*)d_in[13];
  const float* dec_bh    = (const float*)d_in[14];
  const float* out_W     = (const float*)d_in[15];
  const float* out_b     = (const float*)d_in[16];

  char* ws = (char*)d_ws;
  unsigned* cnt   = (unsigned*)(ws + WS_CNT);
  __bf16* encWxT  = (__bf16*)(ws + WS_ENCWXT);
  __bf16* encWhT  = (__bf16*)(ws + WS_ENCWHT);
  __bf16* decWxT  = (__bf16*)(ws + WS_DECWXT);
  __bf16* decWhT  = (__bf16*)(ws + WS_DECWHT);
  __bf16* attnWhT = (__bf16*)(ws + WS_ATTNWHT);
  float*  WsT     = (float*)(ws + WS_WST);
  __bf16* outWT   = (__bf16*)(ws + WS_OUTWT);
  __bf16* embA    = (__bf16*)(ws + WS_EMBA);
  __bf16* Hcat    = (__bf16*)(ws + WS_HCAT);
  __bf16* hEnc    = (__bf16*)(ws + WS_HENC);
  float*  cFin    = (float*)(ws + WS_CFIN);
  __bf16* hDec    = (__bf16*)(ws + WS_HDEC);
  __bf16* xDec    = (__bf16*)(ws + WS_XDEC);
  float*  sBuf    = (float*)(ws + WS_SBUF);
  float*  eBuf    = (float*)(ws + WS_EBUF);

  char* doB = (char*)d_out;               // d_out doubles as scratch pre-final-GEMM
  __bf16* srcZx = (__bf16*)(doB + DO_SRCZX);
  float*  whEnc = (float*)(doB + DO_WHENC);
  __bf16* encHs = (__bf16*)(doB + DO_ENCHS);

  zero_init<<<64, 256, 0, stream>>>(cnt, (unsigned*)hEnc);
  transpose_cvt<__bf16><<<dim3(64, 8),   256, 0, stream>>>(enc_Wx, encWxT, 256, 2048);
  transpose_cvt<__bf16><<<dim3(64, 16),  256, 0, stream>>>(enc_Wh, encWhT, 512, 2048);
  transpose_cvt<__bf16><<<dim3(64, 24),  256, 0, stream>>>(dec_Wx, decWxT, 768, 2048);
  transpose_cvt<__bf16><<<dim3(64, 16),  256, 0, stream>>>(dec_Wh, decWhT, 512, 2048);
  transpose_cvt<__bf16><<<dim3(16, 16),  256, 0, stream>>>(attn_Wh, attnWhT, 512, 512);
  transpose_cvt<float ><<<dim3(16, 16),  256, 0, stream>>>(attn_Ws, WsT, 512, 512);
  transpose_cvt<__bf16><<<dim3(1000, 32), 256, 0, stream>>>(out_W, outWT, 1024, 32000);
  embed_src<<<8192, 256, 0, stream>>>(src, enc_embed, embA);
  gemm128<1><<<dim3(64, 16), 256, 0, stream>>>(embA, encWxT, enc_bx, srcZx, 8192, 2048, 256);
  encoder_kernel<<<64, 256, 0, stream>>>(srcZx, encWhT, enc_bh, hEnc, encHs, cFin, cnt);
  gemm128<0><<<dim3(64, 4), 256, 0, stream>>>(encHs, attnWhT, nullptr, whEnc, 8192, 512, 512);
  decoder_kernel<<<64, 256, 0, stream>>>(tgt, dec_embed, WsT, attn_v, whEnc, encHs,
                                         decWxT, decWhT, dec_bx, dec_bh, cFin,
                                         hDec, xDec, sBuf, eBuf, Hcat, cnt + 1);
  gemm128<2><<<dim3(16, 250), 256, 0, stream>>>(Hcat, outWT, out_b, d_out, 2048, 32000, 1024);
  lsm_kernel<<<2048, 256, 0, stream>>>((float*)d_out);
}